// Round 2
// baseline (245.711 us; speedup 1.0000x reference)
//
#include <hip/hip_runtime.h>
#include <hip/hip_bf16.h>

#define N_NODES_C 20000
#define N_EDGES_C 200000

#define PW0_C       0.17677669529663687f   // sqrt(1/32)
#define PW1_C       0.30618621784789724f   // sqrt(3/32)
#define INV_SQRT3_C 0.57735026918962576f
#define SI_NORM_C   0.25f                  // 1/sqrt(16)

typedef __attribute__((ext_vector_type(8))) short short8;
typedef __attribute__((ext_vector_type(4))) float f32x4;

__device__ __forceinline__ unsigned short f2bf(float x) {
    union { float f; unsigned u; } v; v.f = x;
    unsigned r = v.u + 0x7fffu + ((v.u >> 16) & 1u);   // RNE
    return (unsigned short)(r >> 16);
}

// ---------------- K0: h = silu(edge_attr @ w1 + b1), bf16 ----------------
__global__ __launch_bounds__(256) void k_h(const float* __restrict__ ea,
                                           const float* __restrict__ w1,
                                           const float* __restrict__ b1,
                                           unsigned short* __restrict__ h) {
    int idx = blockIdx.x * 256 + threadIdx.x;        // E*64 = 12.8M exact
    int e = idx >> 6, c = idx & 63;
    const float* a = ea + e * 8;                     // broadcast within wave
    float acc = b1[c];
    #pragma unroll
    for (int k = 0; k < 8; ++k) acc = fmaf(a[k], w1[k * 64 + c], acc);
    float s = acc / (1.0f + __expf(-acc));
    h[idx] = f2bf(s);
}

// ---------------- K0b: repack w2 -> bf16 B-fragment layout ----------------
// dest[tid]: tid = ((u*4+k)*2+ks)*512 + l*8 + j
// value = w2[ ks*32 + (l>>4)*8 + j ][ k*256 + u*16 + (l&15) ]
__global__ __launch_bounds__(256) void k_w2(const float* __restrict__ w2,
                                            unsigned short* __restrict__ w2f) {
    int tid = blockIdx.x * 256 + threadIdx.x;        // 65536 exact
    int j  = tid & 7;
    int l  = (tid >> 3) & 63;
    int ks = (tid >> 9) & 1;
    int tp = tid >> 10;                              // u*4+k
    int u = tp >> 2, k = tp & 3;
    int krow = ks * 32 + (l >> 4) * 8 + j;
    int col  = k * 256 + u * 16 + (l & 15);
    w2f[tid] = f2bf(w2[krow * 1024 + col]);
}

// ---------------- CSR build ----------------
__global__ __launch_bounds__(256) void k_count(const int* __restrict__ ei,
                                               int* __restrict__ cnt) {
    int e = blockIdx.x * 256 + threadIdx.x;
    if (e < N_EDGES_C) atomicAdd(&cnt[ei[e]], 1);
}

// single-block exclusive scan of cnt[0..N_NODES) -> base; base[N]=E
__global__ __launch_bounds__(256) void k_scan(const int* __restrict__ cnt,
                                              int* __restrict__ base) {
    __shared__ int wsum[4];
    __shared__ int carry_s;
    if (threadIdx.x == 0) carry_s = 0;
    int lane = threadIdx.x & 63, wid = threadIdx.x >> 6;
    for (int start = 0; start < N_NODES_C; start += 256) {
        int i = start + threadIdx.x;
        int v = (i < N_NODES_C) ? cnt[i] : 0;
        int x = v;
        #pragma unroll
        for (int d = 1; d < 64; d <<= 1) {
            int y = __shfl_up(x, d);
            if (lane >= d) x += y;
        }
        if (lane == 63) wsum[wid] = x;
        __syncthreads();                       // wsum visible; prev carry update done
        int woff = 0;
        #pragma unroll
        for (int w = 0; w < 4; ++w) if (w < wid) woff += wsum[w];
        int carry = carry_s;
        if (i < N_NODES_C) base[i] = carry + woff + x - v;   // exclusive
        __syncthreads();                       // all reads of carry_s/wsum done
        if (threadIdx.x == 255) carry_s = carry + woff + x;
    }
    if (threadIdx.x == 0) base[N_NODES_C] = N_EDGES_C;
}

__global__ __launch_bounds__(256) void k_fill(const int* __restrict__ ei,
                                              const int* __restrict__ base,
                                              int* __restrict__ cur,
                                              int* __restrict__ eix) {
    int e = blockIdx.x * 256 + threadIdx.x;
    if (e < N_EDGES_C) {
        int r = ei[e];
        int p = atomicAdd(&cur[r], 1);
        eix[base[r] + p] = e;
    }
}

// ---------------- K_main: fused h@w2 (MFMA) + contraction -> msg ----------
__global__ __launch_bounds__(256) void k_main(const float* __restrict__ nf,
                                              const float* __restrict__ sh,
                                              const int* __restrict__ ei,
                                              const unsigned short* __restrict__ h,
                                              const unsigned short* __restrict__ w2f,
                                              const float* __restrict__ b2,
                                              float* __restrict__ msg) {
    __shared__ unsigned short w2s[2][4096];   // 16 KB dbuf; aliased as nf_s in phase A
    __shared__ float S[6][16][64];            // 24 KB: [class][u][edge_local]
    __shared__ float sh_s[64][4];             // 1 KB
    __shared__ float b2_s[4][16][16];         // 4 KB

    float (*nf_s)[64] = (float (*)[64])w2s;   // phase-A alias (dead before w2s use)

    const int t    = threadIdx.x;
    const int e0   = blockIdx.x * 64;
    const int lane = t & 63;
    const int wid  = t >> 6;

    // ---- phase A: gather node rows / sh / b2 ----
    {
        float* b2flat = &b2_s[0][0][0];
        #pragma unroll
        for (int i = 0; i < 4; ++i) b2flat[t + i * 256] = b2[t + i * 256];
        int el = t >> 2, part = t & 3;
        int col = ei[N_EDGES_C + e0 + el];
        const f32x4* src = (const f32x4*)(nf + col * 64);
        #pragma unroll
        for (int q = 0; q < 4; ++q)
            *(f32x4*)&nf_s[el][part * 16 + q * 4] = src[part * 4 + q];
        if (part == 0)
            *(f32x4*)&sh_s[el][0] = *(const f32x4*)(sh + (e0 + el) * 4);
    }
    // A-fragments from h: lane holds row=lane&15, k=(lane>>4)*8+j
    const unsigned short* hrow = h + (e0 + wid * 16 + (lane & 15)) * 64 + ((lane >> 4) * 8);
    short8 a0 = *(const short8*)(hrow);        // k in [0,32)
    short8 a1 = *(const short8*)(hrow + 32);   // k in [32,64)
    __syncthreads();

    // ---- phase B: per-edge scalar classes; prefetch w2 chunk 0 ----
    int4 p0, p1;
    {
        const int4* wsrc = (const int4*)(w2f);
        p0 = wsrc[t]; p1 = wsrc[256 + t];
    }
    {
        int el = t >> 2, part = t & 3;
        float y0 = sh_s[el][0], y1x = sh_s[el][1], y1y = sh_s[el][2], y1z = sh_s[el][3];
        #pragma unroll
        for (int uu = 0; uu < 4; ++uu) {
            int u = part * 4 + uu;
            float xs = nf_s[el][u];
            float v0 = nf_s[el][16 + u * 3 + 0];
            float v1 = nf_s[el][16 + u * 3 + 1];
            float v2 = nf_s[el][16 + u * 3 + 2];
            float dot = v0 * y1x + v1 * y1y + v2 * y1z;
            S[0][u][el] = xs * y0;              // -> Wp0
            S[1][u][el] = xs;                   // -> Wp1
            S[2][u][el] = v0;                   // -> Wp2 (m=0)
            S[3][u][el] = v1;                   // -> Wp2 (m=1)
            S[4][u][el] = v2;                   // -> Wp2 (m=2)
            S[5][u][el] = INV_SQRT3_C * dot;    // -> Wp3
        }
    }
    __syncthreads();
    // ---- phase C: commit chunk 0 to LDS (overwrites nf_s region) ----
    ((int4*)w2s[0])[t] = p0;
    ((int4*)w2s[0])[256 + t] = p1;
    __syncthreads();

    const int wcol = lane & 15;
    const int eS   = wid * 16 + ((lane >> 4) << 2);  // C rows: eS..eS+3 (block-local)

    f32x4 acc0 = {0.f, 0.f, 0.f, 0.f};
    f32x4 tv1  = {0.f, 0.f, 0.f, 0.f};
    f32x4 t2a  = {0.f, 0.f, 0.f, 0.f};
    f32x4 t2b  = {0.f, 0.f, 0.f, 0.f};
    f32x4 t2c  = {0.f, 0.f, 0.f, 0.f};

    for (int u = 0; u < 16; ++u) {
        const int buf = u & 1;
        int4 n0, n1;
        if (u < 15) {   // prefetch next 8 KB chunk (issue early, commit late)
            const int4* wsrc = (const int4*)(w2f + (u + 1) * 4096);
            n0 = wsrc[t]; n1 = wsrc[256 + t];
        }
        f32x4 sA  = *(const f32x4*)&S[0][u][eS];
        f32x4 sX  = *(const f32x4*)&S[1][u][eS];
        f32x4 sV0 = *(const f32x4*)&S[2][u][eS];
        f32x4 sV1 = *(const f32x4*)&S[3][u][eS];
        f32x4 sV2 = *(const f32x4*)&S[4][u][eS];
        f32x4 sB  = *(const f32x4*)&S[5][u][eS];
        #pragma unroll
        for (int k = 0; k < 4; ++k) {
            short8 b0 = *(const short8*)&w2s[buf][(k * 2 + 0) * 512 + lane * 8];
            short8 b1 = *(const short8*)&w2s[buf][(k * 2 + 1) * 512 + lane * 8];
            f32x4 c = {0.f, 0.f, 0.f, 0.f};
            c = __builtin_amdgcn_mfma_f32_16x16x32_bf16(a0, b0, c, 0, 0, 0);
            c = __builtin_amdgcn_mfma_f32_16x16x32_bf16(a1, b1, c, 0, 0, 0);
            float bb = b2_s[k][u][wcol];
            if (k == 0) {
                #pragma unroll
                for (int r = 0; r < 4; ++r) acc0[r] = fmaf(c[r] + bb, sA[r], acc0[r]);
            } else if (k == 1) {
                #pragma unroll
                for (int r = 0; r < 4; ++r) tv1[r] = fmaf(c[r] + bb, sX[r], tv1[r]);
            } else if (k == 2) {
                #pragma unroll
                for (int r = 0; r < 4; ++r) {
                    float wp = c[r] + bb;
                    t2a[r] = fmaf(wp, sV0[r], t2a[r]);
                    t2b[r] = fmaf(wp, sV1[r], t2b[r]);
                    t2c[r] = fmaf(wp, sV2[r], t2c[r]);
                }
            } else {
                #pragma unroll
                for (int r = 0; r < 4; ++r) acc0[r] = fmaf(c[r] + bb, sB[r], acc0[r]);
            }
        }
        if (u < 15) {
            int4* dst = (int4*)w2s[buf ^ 1];
            dst[t] = n0; dst[256 + t] = n1;
        }
        __syncthreads();
    }

    // ---- epilogue: assemble messages, plain coalesced stores ----
    #pragma unroll
    for (int r = 0; r < 4; ++r) {
        int el = eS + r;
        float y0 = sh_s[el][0];
        float* dst = msg + (size_t)(e0 + el) * 64;
        dst[wcol] = PW0_C * acc0[r];
        float tt1 = tv1[r];
        const float c1 = PW1_C * INV_SQRT3_C;
        dst[16 + wcol * 3 + 0] = c1 * (tt1 * sh_s[el][1] + t2a[r] * y0);
        dst[16 + wcol * 3 + 1] = c1 * (tt1 * sh_s[el][2] + t2b[r] * y0);
        dst[16 + wcol * 3 + 2] = c1 * (tt1 * sh_s[el][3] + t2c[r] * y0);
    }
}

// ---------------- K_gather: per-node sum of messages + self-interaction ---
__global__ __launch_bounds__(256) void k_gather(const float* __restrict__ msg,
                                                const int* __restrict__ eix,
                                                const int* __restrict__ base,
                                                const float* __restrict__ nf,
                                                const float* __restrict__ wsi0,
                                                const float* __restrict__ wsi1,
                                                float* __restrict__ out) {
    int wid = threadIdx.x >> 6, lane = threadIdx.x & 63;
    int n = blockIdx.x * 4 + wid;
    if (n >= N_NODES_C) return;
    int b0 = base[n], b1 = base[n + 1];
    float acc = 0.f;
    for (int j = b0; j < b1; ++j) {
        int e = eix[j];                              // wave-uniform
        acc += msg[(size_t)e * 64 + lane];           // 256B coalesced row read
    }
    const float* x = nf + n * 64;
    float si = 0.f;
    if (lane < 16) {
        #pragma unroll
        for (int u = 0; u < 16; ++u) si = fmaf(x[u], wsi0[u * 16 + lane], si);
    } else {
        int w = (lane - 16) / 3, m = (lane - 16) - w * 3;
        #pragma unroll
        for (int u = 0; u < 16; ++u) si = fmaf(x[16 + u * 3 + m], wsi1[u * 16 + w], si);
    }
    out[n * 64 + lane] = acc + si * SI_NORM_C;
}

extern "C" void kernel_launch(void* const* d_in, const int* in_sizes, int n_in,
                              void* d_out, int out_size, void* d_ws, size_t ws_size,
                              hipStream_t stream) {
    const float* nf   = (const float*)d_in[0];
    const float* ea   = (const float*)d_in[1];
    const float* sh   = (const float*)d_in[2];
    const float* w1   = (const float*)d_in[3];
    const float* b1   = (const float*)d_in[4];
    const float* w2   = (const float*)d_in[5];
    const float* b2   = (const float*)d_in[6];
    const float* wsi0 = (const float*)d_in[7];
    const float* wsi1 = (const float*)d_in[8];
    const int*   ei   = (const int*)d_in[9];
    float* out = (float*)d_out;

    // workspace layout
    char* ws = (char*)d_ws;
    float* msg           = (float*)ws;                                  // 51.2 MB
    unsigned short* h    = (unsigned short*)(ws + 51200000);            // 25.6 MB
    unsigned short* w2f  = (unsigned short*)(ws + 51200000 + 25600000); // 128 KB
    int* cnt             = (int*)(ws + 51200000 + 25600000 + 131072);   // 80 KB
    int* cur             = cnt + N_NODES_C;                              // 80 KB
    int* base            = cur + N_NODES_C;                              // 80 KB+4
    int* eix             = base + N_NODES_C + 1;                         // 800 KB

    hipMemsetAsync(cnt, 0, 2 * N_NODES_C * sizeof(int), stream);  // cnt + cur

    k_h    <<<50000, 256, 0, stream>>>(ea, w1, b1, h);
    k_w2   <<<256,   256, 0, stream>>>(w2, w2f);
    k_count<<<(N_EDGES_C + 255) / 256, 256, 0, stream>>>(ei, cnt);
    k_scan <<<1,     256, 0, stream>>>(cnt, base);
    k_fill <<<(N_EDGES_C + 255) / 256, 256, 0, stream>>>(ei, base, cur, eix);
    k_main <<<3125,  256, 0, stream>>>(nf, sh, ei, h, w2f, b2, msg);
    k_gather<<<5000, 256, 0, stream>>>(msg, eix, base, nf, wsi0, wsi1, out);
}

// Round 3
// 202.351 us; speedup vs baseline: 1.2143x; 1.2143x over previous
//
#include <hip/hip_runtime.h>
#include <hip/hip_bf16.h>

#define N_NODES_C 20000
#define N_EDGES_C 200000

#define PW0_C       0.17677669529663687f   // sqrt(1/32)
#define PW1_C       0.30618621784789724f   // sqrt(3/32)
#define INV_SQRT3_C 0.57735026918962576f
#define SI_NORM_C   0.25f                  // 1/sqrt(16)

typedef __attribute__((ext_vector_type(8))) short short8;
typedef __attribute__((ext_vector_type(4))) float f32x4;

__device__ __forceinline__ unsigned short f2bf(float x) {
    union { float f; unsigned u; } v; v.f = x;
    unsigned r = v.u + 0x7fffu + ((v.u >> 16) & 1u);   // RNE
    return (unsigned short)(r >> 16);
}

// ---------------- K0: h = silu(edge_attr @ w1 + b1), bf16 ----------------
__global__ __launch_bounds__(256) void k_h(const float* __restrict__ ea,
                                           const float* __restrict__ w1,
                                           const float* __restrict__ b1,
                                           unsigned short* __restrict__ h) {
    int idx = blockIdx.x * 256 + threadIdx.x;        // E*64 = 12.8M exact
    int e = idx >> 6, c = idx & 63;
    const float* a = ea + e * 8;
    float acc = b1[c];
    #pragma unroll
    for (int k = 0; k < 8; ++k) acc = fmaf(a[k], w1[k * 64 + c], acc);
    float s = acc / (1.0f + __expf(-acc));
    h[idx] = f2bf(s);
}

// ---------------- K0b: repack w2 -> bf16 B-fragment layout ----------------
// dest[tid]: tid = ((u*4+k)*2+ks)*512 + l*8 + j
// value = w2[ ks*32 + (l>>4)*8 + j ][ k*256 + u*16 + (l&15) ]
__global__ __launch_bounds__(256) void k_w2(const float* __restrict__ w2,
                                            unsigned short* __restrict__ w2f) {
    int tid = blockIdx.x * 256 + threadIdx.x;        // 65536 exact
    int j  = tid & 7;
    int l  = (tid >> 3) & 63;
    int ks = (tid >> 9) & 1;
    int tp = tid >> 10;                              // u*4+k
    int u = tp >> 2, k = tp & 3;
    int krow = ks * 32 + (l >> 4) * 8 + j;
    int col  = k * 256 + u * 16 + (l & 15);
    w2f[tid] = f2bf(w2[krow * 1024 + col]);
}

// ---------------- CSR build ----------------
__global__ __launch_bounds__(256) void k_count(const int* __restrict__ ei,
                                               int* __restrict__ cnt) {
    int e = blockIdx.x * 256 + threadIdx.x;
    if (e < N_EDGES_C) atomicAdd(&cnt[ei[e]], 1);
}

// single-block (1024 thr) exclusive scan of cnt[0..N_NODES) -> base; base[N]=E
__global__ __launch_bounds__(1024) void k_scan(const int* __restrict__ cnt,
                                               int* __restrict__ base) {
    __shared__ int wsum[16];
    __shared__ int carry_s;
    if (threadIdx.x == 0) carry_s = 0;
    int lane = threadIdx.x & 63, wid = threadIdx.x >> 6;
    __syncthreads();
    for (int start = 0; start < N_NODES_C; start += 1024) {
        int i = start + threadIdx.x;
        int v = (i < N_NODES_C) ? cnt[i] : 0;
        int x = v;
        #pragma unroll
        for (int d = 1; d < 64; d <<= 1) {
            int y = __shfl_up(x, d);
            if (lane >= d) x += y;
        }
        if (lane == 63) wsum[wid] = x;
        __syncthreads();
        int woff = 0;
        #pragma unroll
        for (int w = 0; w < 16; ++w) if (w < wid) woff += wsum[w];
        int carry = carry_s;
        if (i < N_NODES_C) base[i] = carry + woff + x - v;   // exclusive
        __syncthreads();
        if (threadIdx.x == 1023) carry_s = carry + woff + x;
    }
    if (threadIdx.x == 0) base[N_NODES_C] = N_EDGES_C;
}

__global__ __launch_bounds__(256) void k_fill(const int* __restrict__ ei,
                                              const int* __restrict__ base,
                                              int* __restrict__ cur,
                                              int* __restrict__ eix) {
    int e = blockIdx.x * 256 + threadIdx.x;
    if (e < N_EDGES_C) {
        int r = ei[e];
        int p = atomicAdd(&cur[r], 1);
        eix[base[r] + p] = e;
    }
}

// ---------------- K_main: B-in-registers, k-specialized waves -------------
// Block: 4 waves, 64 edges. Wave w holds k-class w's 16 B-frag pairs in regs.
// No barriers / no LDS traffic for B in the inner loop.
__global__ __launch_bounds__(256, 2) void k_main(const float* __restrict__ nf,
                                                 const float* __restrict__ sh,
                                                 const int* __restrict__ ei,
                                                 const unsigned short* __restrict__ h,
                                                 const unsigned short* __restrict__ w2f,
                                                 const float* __restrict__ b2,
                                                 float* __restrict__ msg) {
    __shared__ __align__(16) char uni[24576];  // nf_s (16KB, phase A/B) -> partials (24KB)
    __shared__ float S[6][16][64];             // 24 KB: [class][u][edge_local]
    __shared__ float sh_s[64][4];              // 1 KB
    __shared__ float b2_s[4][16][16];          // 4 KB

    float (*nf_s)[64] = (float (*)[64])uni;
    float (*P0)[16]   = (float (*)[16])uni;            // k=0 partial  [64][16]
    float (*P1)[16]   = (float (*)[16])(uni + 4096);   // k=1 partial
    float (*P3)[16]   = (float (*)[16])(uni + 8192);   // k=3 partial
    float (*Q)[64][16] = (float (*)[64][16])(uni + 12288); // k=2, m=0..2

    const int t    = threadIdx.x;
    const int e0   = blockIdx.x * 64;
    const int lane = t & 63;
    const int wid  = t >> 6;

    // ---- phase A: gather node rows / sh / b2 ----
    {
        float* b2flat = &b2_s[0][0][0];
        #pragma unroll
        for (int i = 0; i < 4; ++i) b2flat[t + i * 256] = b2[t + i * 256];
        int el = t >> 2, part = t & 3;
        int col = ei[N_EDGES_C + e0 + el];
        const f32x4* src = (const f32x4*)(nf + col * 64);
        #pragma unroll
        for (int q = 0; q < 4; ++q)
            *(f32x4*)&nf_s[el][part * 16 + q * 4] = src[part * 4 + q];
        if (part == 0)
            *(f32x4*)&sh_s[el][0] = *(const f32x4*)(sh + (e0 + el) * 4);
    }
    // B-fragments for this wave's k-class -> registers (32x short8 = 128 VGPR)
    short8 B0[16], B1[16];
    {
        const unsigned short* wk = w2f + wid * 1024 + lane * 8;
        #pragma unroll
        for (int u = 0; u < 16; ++u) {
            B0[u] = *(const short8*)&wk[u * 4096];
            B1[u] = *(const short8*)&wk[u * 4096 + 512];
        }
    }
    __syncthreads();

    // ---- phase B: per-edge scalar classes ----
    {
        int el = t >> 2, part = t & 3;
        float y0 = sh_s[el][0], y1x = sh_s[el][1], y1y = sh_s[el][2], y1z = sh_s[el][3];
        #pragma unroll
        for (int uu = 0; uu < 4; ++uu) {
            int u = part * 4 + uu;
            float xs = nf_s[el][u];
            float v0 = nf_s[el][16 + u * 3 + 0];
            float v1 = nf_s[el][16 + u * 3 + 1];
            float v2 = nf_s[el][16 + u * 3 + 2];
            float dot = v0 * y1x + v1 * y1y + v2 * y1z;
            S[0][u][el] = xs * y0;
            S[1][u][el] = xs;
            S[2][u][el] = v0;
            S[3][u][el] = v1;
            S[4][u][el] = v2;
            S[5][u][el] = INV_SQRT3_C * dot;
        }
    }
    __syncthreads();   // S ready; nf_s dead -> partials region reusable

    const int wcol = lane & 15;
    const int g4   = (lane >> 4) << 2;   // row group base within tile

    // ---- compute: each wave does its k-class for all 4 A-tiles ----
    #define TILE_PROLOG(tt)                                                          \
        const unsigned short* hrow = h + (size_t)(e0 + (tt) * 16 + (lane & 15)) * 64 \
                                       + ((lane >> 4) * 8);                          \
        short8 a0 = *(const short8*)(hrow);                                          \
        short8 a1 = *(const short8*)(hrow + 32);

    if (wid == 0) {
        #pragma unroll 1
        for (int tt = 0; tt < 4; ++tt) {
            TILE_PROLOG(tt)
            f32x4 acc = {0.f, 0.f, 0.f, 0.f};
            #pragma unroll
            for (int u = 0; u < 16; ++u) {
                f32x4 c = {0.f, 0.f, 0.f, 0.f};
                c = __builtin_amdgcn_mfma_f32_16x16x32_bf16(a0, B0[u], c, 0, 0, 0);
                c = __builtin_amdgcn_mfma_f32_16x16x32_bf16(a1, B1[u], c, 0, 0, 0);
                float bb = b2_s[0][u][wcol];
                f32x4 s = *(const f32x4*)&S[0][u][tt * 16 + g4];
                #pragma unroll
                for (int r = 0; r < 4; ++r) acc[r] = fmaf(c[r] + bb, s[r], acc[r]);
            }
            #pragma unroll
            for (int r = 0; r < 4; ++r) P0[tt * 16 + g4 + r][wcol] = acc[r];
        }
    } else if (wid == 1) {
        #pragma unroll 1
        for (int tt = 0; tt < 4; ++tt) {
            TILE_PROLOG(tt)
            f32x4 acc = {0.f, 0.f, 0.f, 0.f};
            #pragma unroll
            for (int u = 0; u < 16; ++u) {
                f32x4 c = {0.f, 0.f, 0.f, 0.f};
                c = __builtin_amdgcn_mfma_f32_16x16x32_bf16(a0, B0[u], c, 0, 0, 0);
                c = __builtin_amdgcn_mfma_f32_16x16x32_bf16(a1, B1[u], c, 0, 0, 0);
                float bb = b2_s[1][u][wcol];
                f32x4 s = *(const f32x4*)&S[1][u][tt * 16 + g4];
                #pragma unroll
                for (int r = 0; r < 4; ++r) acc[r] = fmaf(c[r] + bb, s[r], acc[r]);
            }
            #pragma unroll
            for (int r = 0; r < 4; ++r) P1[tt * 16 + g4 + r][wcol] = acc[r];
        }
    } else if (wid == 2) {
        #pragma unroll 1
        for (int tt = 0; tt < 4; ++tt) {
            TILE_PROLOG(tt)
            f32x4 qa = {0.f,0.f,0.f,0.f}, qb = {0.f,0.f,0.f,0.f}, qc = {0.f,0.f,0.f,0.f};
            #pragma unroll
            for (int u = 0; u < 16; ++u) {
                f32x4 c = {0.f, 0.f, 0.f, 0.f};
                c = __builtin_amdgcn_mfma_f32_16x16x32_bf16(a0, B0[u], c, 0, 0, 0);
                c = __builtin_amdgcn_mfma_f32_16x16x32_bf16(a1, B1[u], c, 0, 0, 0);
                float bb = b2_s[2][u][wcol];
                f32x4 s0 = *(const f32x4*)&S[2][u][tt * 16 + g4];
                f32x4 s1 = *(const f32x4*)&S[3][u][tt * 16 + g4];
                f32x4 s2 = *(const f32x4*)&S[4][u][tt * 16 + g4];
                #pragma unroll
                for (int r = 0; r < 4; ++r) {
                    float wp = c[r] + bb;
                    qa[r] = fmaf(wp, s0[r], qa[r]);
                    qb[r] = fmaf(wp, s1[r], qb[r]);
                    qc[r] = fmaf(wp, s2[r], qc[r]);
                }
            }
            #pragma unroll
            for (int r = 0; r < 4; ++r) {
                Q[0][tt * 16 + g4 + r][wcol] = qa[r];
                Q[1][tt * 16 + g4 + r][wcol] = qb[r];
                Q[2][tt * 16 + g4 + r][wcol] = qc[r];
            }
        }
    } else {
        #pragma unroll 1
        for (int tt = 0; tt < 4; ++tt) {
            TILE_PROLOG(tt)
            f32x4 acc = {0.f, 0.f, 0.f, 0.f};
            #pragma unroll
            for (int u = 0; u < 16; ++u) {
                f32x4 c = {0.f, 0.f, 0.f, 0.f};
                c = __builtin_amdgcn_mfma_f32_16x16x32_bf16(a0, B0[u], c, 0, 0, 0);
                c = __builtin_amdgcn_mfma_f32_16x16x32_bf16(a1, B1[u], c, 0, 0, 0);
                float bb = b2_s[3][u][wcol];
                f32x4 s = *(const f32x4*)&S[5][u][tt * 16 + g4];
                #pragma unroll
                for (int r = 0; r < 4; ++r) acc[r] = fmaf(c[r] + bb, s[r], acc[r]);
            }
            #pragma unroll
            for (int r = 0; r < 4; ++r) P3[tt * 16 + g4 + r][wcol] = acc[r];
        }
    }
    #undef TILE_PROLOG
    __syncthreads();

    // ---- assembly: thread = (edge-group eg, channel c); coalesced stores ----
    {
        int c  = t & 63;
        int eg = t >> 6;
        if (c < 16) {
            #pragma unroll
            for (int i = 0; i < 16; ++i) {
                int e = eg * 16 + i;
                msg[(size_t)(e0 + e) * 64 + c] = PW0_C * (P0[e][c] + P3[e][c]);
            }
        } else {
            const float c1 = PW1_C * INV_SQRT3_C;
            int w = (c - 16) / 3, m = (c - 16) - 3 * w;
            #pragma unroll
            for (int i = 0; i < 16; ++i) {
                int e = eg * 16 + i;
                msg[(size_t)(e0 + e) * 64 + c] =
                    c1 * (P1[e][w] * sh_s[e][1 + m] + Q[m][e][w] * sh_s[e][0]);
            }
        }
    }
}

// ---------------- K_gather: per-node sum of messages + self-interaction ---
__global__ __launch_bounds__(256) void k_gather(const float* __restrict__ msg,
                                                const int* __restrict__ eix,
                                                const int* __restrict__ base,
                                                const float* __restrict__ nf,
                                                const float* __restrict__ wsi0,
                                                const float* __restrict__ wsi1,
                                                float* __restrict__ out) {
    int wid = threadIdx.x >> 6, lane = threadIdx.x & 63;
    int n = blockIdx.x * 4 + wid;
    if (n >= N_NODES_C) return;
    int b0 = base[n], b1 = base[n + 1];
    float acc = 0.f;
    int j = b0;
    for (; j + 4 <= b1; j += 4) {          // 4-way ILP: independent 256B row reads
        int ea0 = eix[j], ea1 = eix[j + 1], ea2 = eix[j + 2], ea3 = eix[j + 3];
        float v0 = msg[(size_t)ea0 * 64 + lane];
        float v1 = msg[(size_t)ea1 * 64 + lane];
        float v2 = msg[(size_t)ea2 * 64 + lane];
        float v3 = msg[(size_t)ea3 * 64 + lane];
        acc += (v0 + v1) + (v2 + v3);
    }
    for (; j < b1; ++j) acc += msg[(size_t)eix[j] * 64 + lane];
    const float* x = nf + n * 64;
    float si = 0.f;
    if (lane < 16) {
        #pragma unroll
        for (int u = 0; u < 16; ++u) si = fmaf(x[u], wsi0[u * 16 + lane], si);
    } else {
        int w = (lane - 16) / 3, m = (lane - 16) - w * 3;
        #pragma unroll
        for (int u = 0; u < 16; ++u) si = fmaf(x[16 + u * 3 + m], wsi1[u * 16 + w], si);
    }
    out[n * 64 + lane] = acc + si * SI_NORM_C;
}

extern "C" void kernel_launch(void* const* d_in, const int* in_sizes, int n_in,
                              void* d_out, int out_size, void* d_ws, size_t ws_size,
                              hipStream_t stream) {
    const float* nf   = (const float*)d_in[0];
    const float* ea   = (const float*)d_in[1];
    const float* sh   = (const float*)d_in[2];
    const float* w1   = (const float*)d_in[3];
    const float* b1   = (const float*)d_in[4];
    const float* w2   = (const float*)d_in[5];
    const float* b2   = (const float*)d_in[6];
    const float* wsi0 = (const float*)d_in[7];
    const float* wsi1 = (const float*)d_in[8];
    const int*   ei   = (const int*)d_in[9];
    float* out = (float*)d_out;

    // workspace layout
    char* ws = (char*)d_ws;
    float* msg           = (float*)ws;                                  // 51.2 MB
    unsigned short* h    = (unsigned short*)(ws + 51200000);            // 25.6 MB
    unsigned short* w2f  = (unsigned short*)(ws + 51200000 + 25600000); // 128 KB
    int* cnt             = (int*)(ws + 51200000 + 25600000 + 131072);
    int* cur             = cnt + N_NODES_C;
    int* base            = cur + N_NODES_C;
    int* eix             = base + N_NODES_C + 1;

    hipMemsetAsync(cnt, 0, 2 * N_NODES_C * sizeof(int), stream);  // cnt + cur

    k_h    <<<50000, 256, 0, stream>>>(ea, w1, b1, h);
    k_w2   <<<256,   256, 0, stream>>>(w2, w2f);
    k_count<<<(N_EDGES_C + 255) / 256, 256, 0, stream>>>(ei, cnt);
    k_scan <<<1,    1024, 0, stream>>>(cnt, base);
    k_fill <<<(N_EDGES_C + 255) / 256, 256, 0, stream>>>(ei, base, cur, eix);
    k_main <<<3125,  256, 0, stream>>>(nf, sh, ei, h, w2f, b2, msg);
    k_gather<<<5000, 256, 0, stream>>>(msg, eix, base, nf, wsi0, wsi1, out);
}